// Round 1
// baseline (597.430 us; speedup 1.0000x reference)
//
#include <hip/hip_runtime.h>

#define BB 16
#define SS 4096
#define HH 1024
#define SPLIT 128
#define CHUNK (SS / SPLIT)   // 32 rows per context block

__device__ __forceinline__ float fast_tanh(float x) {
    // clamp so exp never overflows to inf (tanh saturated anyway)
    x = fminf(fmaxf(x, -15.0f), 15.0f);
    float e = __expf(-2.0f * x);
    return (1.0f - e) * __builtin_amdgcn_rcpf(1.0f + e);
}

__device__ __forceinline__ float wave_reduce_sum(float v) {
#pragma unroll
    for (int off = 32; off > 0; off >>= 1) v += __shfl_xor(v, off, 64);
    return v;
}

// K1: dec_fea[b,h] = sum_k s_t_hat[b,k] * W_dec[h,k] + b_dec[h]
// one wave per (b,h); float4 coalesced loads; wave reduce.
// Also zeroes the per-batch softmax accumulators (stats) for K2's atomics.
__global__ __launch_bounds__(256) void dec_fea_kernel(
    const float* __restrict__ s_t_hat, const float* __restrict__ W_dec,
    const float* __restrict__ b_dec, float* __restrict__ dec_fea,
    float* __restrict__ stats)
{
    if (blockIdx.x == 0) stats[threadIdx.x] = 0.0f;  // 256 floats (16 b x 16 pad)
    int wave = (blockIdx.x * blockDim.x + threadIdx.x) >> 6;  // 0..B*H-1
    int lane = threadIdx.x & 63;
    int b = wave >> 10;
    int h = wave & (HH - 1);
    const float4* st4 = (const float4*)(s_t_hat + (size_t)b * HH);
    const float4* wd4 = (const float4*)(W_dec + (size_t)h * HH);
    float acc = 0.0f;
#pragma unroll
    for (int j = 0; j < 4; ++j) {
        int idx = lane + 64 * j;
        float4 a = st4[idx];
        float4 w = wd4[idx];
        acc += a.x * w.x + a.y * w.y + a.z * w.z + a.w * w.w;
    }
    acc = wave_reduce_sum(acc);
    if (lane == 0) dec_fea[wave] = acc + b_dec[h];
}

// K2: scores[row] = sum_h tanh(ef[row,h] + dec_fea[b,h] + cov[row]*W_c[h]) * v[h]
// one wave per row, fully coalesced. Epilogue fuses the softmax numerator:
// e = exp(score) (no max-subtraction: |score| <= ||v||_1 ~ 25.6, exp safe in
// fp32, and softmax is shift-invariant), t = e*mask -> tbuf, and per-batch
// sums Sigma_e / Sigma_t via one atomicAdd pair per block (all 4 rows of a
// block share b since 4096 % 4 == 0).
__global__ __launch_bounds__(256) void scores_kernel(
    const float* __restrict__ ef, const float* __restrict__ dec_fea,
    const float* __restrict__ cov, const float* __restrict__ W_c,
    const float* __restrict__ v, const float* __restrict__ mask,
    float* __restrict__ scores, float* __restrict__ tbuf,
    float* __restrict__ stats)
{
    int row = (blockIdx.x * blockDim.x + threadIdx.x) >> 6;  // 0..B*S-1
    int lane = threadIdx.x & 63;
    int wid = threadIdx.x >> 6;
    int b = row >> 12;  // S = 4096
    float cv = cov[row];
    const float4* ef4 = (const float4*)(ef + (size_t)row * HH);
    const float4* de4 = (const float4*)(dec_fea + (size_t)b * HH);
    const float4* wc4 = (const float4*)W_c;
    const float4* v4  = (const float4*)v;
    float acc = 0.0f;
#pragma unroll
    for (int j = 0; j < 4; ++j) {
        int idx = lane + 64 * j;
        float4 x  = ef4[idx];
        float4 d  = de4[idx];
        float4 w  = wc4[idx];
        float4 vv = v4[idx];
        acc += fast_tanh(x.x + d.x + cv * w.x) * vv.x;
        acc += fast_tanh(x.y + d.y + cv * w.y) * vv.y;
        acc += fast_tanh(x.z + d.z + cv * w.z) * vv.z;
        acc += fast_tanh(x.w + d.w + cv * w.w) * vv.w;
    }
    acc = wave_reduce_sum(acc);

    __shared__ float sh_e[4];
    __shared__ float sh_t[4];
    if (lane == 0) {
        scores[row] = acc;
        float e = __expf(acc);
        float t = e * mask[row];
        tbuf[row] = t;
        sh_e[wid] = e;
        sh_t[wid] = t;
    }
    __syncthreads();
    if (threadIdx.x == 0) {
        atomicAdd(&stats[b * 16 + 0], sh_e[0] + sh_e[1] + sh_e[2] + sh_e[3]);
        atomicAdd(&stats[b * 16 + 1], sh_t[0] + sh_t[1] + sh_t[2] + sh_t[3]);
    }
}

// K3: partials[split][b][h] = sum_{s in chunk} t[b,s] * eo[b,s,h]
// UNNORMALIZED weights t -> no dependency on the softmax denominator, so this
// streams encoder_outputs immediately after K2. grid (SPLIT, B), 256 threads,
// 2048 blocks = 8 blocks/CU. Deterministic partials (no atomics).
__global__ __launch_bounds__(256) void context_partial_kernel(
    const float* __restrict__ eo, const float* __restrict__ tbuf,
    float* __restrict__ partials)
{
    int b = blockIdx.y;
    int s0 = blockIdx.x * CHUNK;
    int tid = threadIdx.x;
    const float4* eo4 = (const float4*)(eo + ((size_t)b * SS + s0) * HH);
    const float* tt = tbuf + (size_t)b * SS + s0;
    float4 acc = {0.0f, 0.0f, 0.0f, 0.0f};
#pragma unroll 8
    for (int s = 0; s < CHUNK; ++s) {
        float a = tt[s];
        float4 x = eo4[(size_t)s * (HH / 4) + tid];
        acc.x += a * x.x; acc.y += a * x.y; acc.z += a * x.z; acc.w += a * x.w;
    }
    float4* dst = (float4*)(partials + ((size_t)blockIdx.x * BB + b) * HH);
    dst[tid] = acc;
}

// K4: finalize. scale_b = 1/(Sigma_t + 1e-20*Sigma_e)  (== reference's
// (1/Se) / (St/Se + 1e-20) order). Blocks 0..63: attn1/attn2 = t*scale
// (one float4 of B*S per thread). Blocks 64..79: c_t = scale * sum_split
// partials (one float4 of B*H per thread) — absorbs the old reduce kernel.
__global__ __launch_bounds__(256) void finalize_kernel(
    const float* __restrict__ tbuf, const float* __restrict__ partials,
    const float* __restrict__ stats, float* __restrict__ attn1,
    float* __restrict__ attn2, float* __restrict__ c_t)
{
    int tid = threadIdx.x;
    if (blockIdx.x < 64) {
        int g = blockIdx.x * 256 + tid;         // float4 index over B*S (16384)
        int b = g >> 10;                         // 1024 float4 per batch row
        float se = stats[b * 16 + 0];
        float st = stats[b * 16 + 1];
        float scale = 1.0f / (st + 1e-20f * se);
        float4 t = ((const float4*)tbuf)[g];
        float4 a;
        a.x = t.x * scale; a.y = t.y * scale; a.z = t.z * scale; a.w = t.w * scale;
        ((float4*)attn1)[g] = a;
        ((float4*)attn2)[g] = a;
    } else {
        int ci = (blockIdx.x - 64) * 256 + tid;  // float4 index over B*H (4096)
        int b = ci >> 8;                          // 256 float4 per batch
        float se = stats[b * 16 + 0];
        float st = stats[b * 16 + 1];
        float scale = 1.0f / (st + 1e-20f * se);
        const float4* p4 = (const float4*)partials;
        float4 acc = {0.0f, 0.0f, 0.0f, 0.0f};
#pragma unroll 8
        for (int s = 0; s < SPLIT; ++s) {
            float4 x = p4[(size_t)s * (BB * HH / 4) + ci];
            acc.x += x.x; acc.y += x.y; acc.z += x.z; acc.w += x.w;
        }
        acc.x *= scale; acc.y *= scale; acc.z *= scale; acc.w *= scale;
        ((float4*)c_t)[ci] = acc;
    }
}

extern "C" void kernel_launch(void* const* d_in, const int* in_sizes, int n_in,
                              void* d_out, int out_size, void* d_ws, size_t ws_size,
                              hipStream_t stream)
{
    const float* s_t_hat  = (const float*)d_in[0];
    const float* enc_out  = (const float*)d_in[1];
    const float* enc_feat = (const float*)d_in[2];
    const float* mask     = (const float*)d_in[3];
    const float* cov      = (const float*)d_in[4];
    const float* W_dec    = (const float*)d_in[5];
    const float* b_dec    = (const float*)d_in[6];
    const float* W_c      = (const float*)d_in[7];
    const float* v        = (const float*)d_in[8];

    float* out    = (float*)d_out;
    float* c_t    = out;                    // B*H
    float* attn1  = out + BB * HH;          // B*S
    float* attn2  = attn1 + BB * SS;        // B*S
    float* scores = attn2 + BB * SS;        // B*S

    float* dec_fea  = (float*)d_ws;                 // B*H floats
    float* tbuf     = dec_fea + BB * HH;            // B*S floats (e*mask)
    float* stats    = tbuf + BB * SS;               // 16 b x {Sigma_e, Sigma_t}, 64B-padded
    float* partials = stats + 256;                  // SPLIT*B*H floats (8 MB)

    dec_fea_kernel<<<dim3(BB * HH / 4), 256, 0, stream>>>(s_t_hat, W_dec, b_dec, dec_fea, stats);
    scores_kernel<<<dim3(BB * SS / 4), 256, 0, stream>>>(enc_feat, dec_fea, cov, W_c, v, mask,
                                                         scores, tbuf, stats);
    context_partial_kernel<<<dim3(SPLIT, BB), 256, 0, stream>>>(enc_out, tbuf, partials);
    finalize_kernel<<<dim3(80), 256, 0, stream>>>(tbuf, partials, stats, attn1, attn2, c_t);
}

// Round 3
// 537.027 us; speedup vs baseline: 1.1125x; 1.1125x over previous
//
#include <hip/hip_runtime.h>

#define BB 16
#define SS 4096
#define HH 1024
#define SPLIT 128
#define CHUNK (SS / SPLIT)   // 32 rows per context block

__device__ __forceinline__ float fast_tanh(float x) {
    // clamp so exp never overflows to inf (tanh saturated anyway)
    x = fminf(fmaxf(x, -15.0f), 15.0f);
    float e = __expf(-2.0f * x);
    return (1.0f - e) * __builtin_amdgcn_rcpf(1.0f + e);
}

__device__ __forceinline__ float wave_reduce_sum(float v) {
#pragma unroll
    for (int off = 32; off > 0; off >>= 1) v += __shfl_xor(v, off, 64);
    return v;
}

__device__ __forceinline__ float dot_tanh4(float4 x, float4 d, float c,
                                           float4 w, float4 vv) {
    return fast_tanh(x.x + d.x + c * w.x) * vv.x
         + fast_tanh(x.y + d.y + c * w.y) * vv.y
         + fast_tanh(x.z + d.z + c * w.z) * vv.z
         + fast_tanh(x.w + d.w + c * w.w) * vv.w;
}

// K1: dec_fea[b,h] = sum_k s_t_hat[b,k] * W_dec[h,k] + b_dec[h]
// one wave per (b,h); float4 coalesced loads; wave reduce.
// Also zeroes the per-batch softmax accumulators (stats) for K2's atomics.
__global__ __launch_bounds__(256) void dec_fea_kernel(
    const float* __restrict__ s_t_hat, const float* __restrict__ W_dec,
    const float* __restrict__ b_dec, float* __restrict__ dec_fea,
    float* __restrict__ stats)
{
    if (blockIdx.x == 0) stats[threadIdx.x] = 0.0f;  // 256 floats (16 b x 16 pad)
    int wave = (blockIdx.x * blockDim.x + threadIdx.x) >> 6;  // 0..B*H-1
    int lane = threadIdx.x & 63;
    int b = wave >> 10;
    int h = wave & (HH - 1);
    const float4* st4 = (const float4*)(s_t_hat + (size_t)b * HH);
    const float4* wd4 = (const float4*)(W_dec + (size_t)h * HH);
    float acc = 0.0f;
#pragma unroll
    for (int j = 0; j < 4; ++j) {
        int idx = lane + 64 * j;
        float4 a = st4[idx];
        float4 w = wd4[idx];
        acc += a.x * w.x + a.y * w.y + a.z * w.z + a.w * w.w;
    }
    acc = wave_reduce_sum(acc);
    if (lane == 0) dec_fea[wave] = acc + b_dec[h];
}

// K2: 4 ROWS PER WAVE. scores[r] = sum_h tanh(ef[r,h]+dec_fea[b,h]+cov[r]*W_c[h])*v[h]
// dec_fea/W_c/v loaded ONCE per j and shared by 4 rows (4x less broadcast
// traffic); 4 independent ef streams -> 7 outstanding loads per step instead
// of ~4 (round-1 counters: VALUBusy 17%, hbm 10% => latency-stalled at
// VGPR=32). Epilogue fuses softmax numerator: e = exp(score) (|score| <=
// ||v||_1 ~ 26, fp32-safe, softmax shift-invariant), t = e*mask -> tbuf
// (float4 stores), per-batch Sigma_e/Sigma_t via one atomic pair per block.
__global__ __launch_bounds__(256) void scores_kernel(
    const float* __restrict__ ef, const float* __restrict__ dec_fea,
    const float* __restrict__ cov, const float* __restrict__ W_c,
    const float* __restrict__ v, const float* __restrict__ mask,
    float* __restrict__ scores, float* __restrict__ tbuf,
    float* __restrict__ stats)
{
    int wave = (blockIdx.x * blockDim.x + threadIdx.x) >> 6;  // 0..B*S/4-1
    int lane = threadIdx.x & 63;
    int wid = threadIdx.x >> 6;
    int r0 = wave << 2;          // first of 4 consecutive rows (same batch)
    int b = wave >> 10;          // r0 >> 12
    float4 cvv = ((const float4*)cov)[wave];   // cov[r0..r0+3], broadcast
    const float4* e0p = (const float4*)(ef + (size_t)r0 * HH);  // rows stride 256 f4
    const float4* de4 = (const float4*)(dec_fea + (size_t)b * HH);
    const float4* wc4 = (const float4*)W_c;
    const float4* v4  = (const float4*)v;
    float a0 = 0.0f, a1 = 0.0f, a2 = 0.0f, a3 = 0.0f;
#pragma unroll
    for (int j = 0; j < 4; ++j) {
        int idx = lane + 64 * j;
        float4 d  = de4[idx];
        float4 w  = wc4[idx];
        float4 vv = v4[idx];
        float4 x0 = e0p[idx];
        float4 x1 = e0p[256 + idx];
        float4 x2 = e0p[512 + idx];
        float4 x3 = e0p[768 + idx];
        a0 += dot_tanh4(x0, d, cvv.x, w, vv);
        a1 += dot_tanh4(x1, d, cvv.y, w, vv);
        a2 += dot_tanh4(x2, d, cvv.z, w, vv);
        a3 += dot_tanh4(x3, d, cvv.w, w, vv);
    }
    a0 = wave_reduce_sum(a0);
    a1 = wave_reduce_sum(a1);
    a2 = wave_reduce_sum(a2);
    a3 = wave_reduce_sum(a3);

    __shared__ float sh_e[4];
    __shared__ float sh_t[4];
    if (lane == 0) {
        float4 sc = {a0, a1, a2, a3};
        ((float4*)scores)[wave] = sc;
        float4 m = ((const float4*)mask)[wave];
        float e0 = __expf(a0), e1 = __expf(a1), e2 = __expf(a2), e3 = __expf(a3);
        float4 t = {e0 * m.x, e1 * m.y, e2 * m.z, e3 * m.w};
        ((float4*)tbuf)[wave] = t;
        sh_e[wid] = e0 + e1 + e2 + e3;
        sh_t[wid] = t.x + t.y + t.z + t.w;
    }
    __syncthreads();
    if (threadIdx.x == 0) {
        atomicAdd(&stats[b * 16 + 0], sh_e[0] + sh_e[1] + sh_e[2] + sh_e[3]);
        atomicAdd(&stats[b * 16 + 1], sh_t[0] + sh_t[1] + sh_t[2] + sh_t[3]);
    }
}

// K3: partials[split][b][h] = sum_{s in chunk} t[b,s] * eo[b,s,h]
// Unnormalized weights -> no softmax dependency. 4 independent eo streams +
// float4 weight load; unroll 2 => ~8 loads in flight. grid (SPLIT, B) = 2048
// blocks. Deterministic partials (no atomics).
__global__ __launch_bounds__(256) void context_partial_kernel(
    const float* __restrict__ eo, const float* __restrict__ tbuf,
    float* __restrict__ partials)
{
    int b = blockIdx.y;
    int s0 = blockIdx.x * CHUNK;
    int tid = threadIdx.x;
    const float4* eo4 = (const float4*)(eo + ((size_t)b * SS + s0) * HH);
    const float* tt = tbuf + (size_t)b * SS + s0;
    float4 acc0 = {0, 0, 0, 0}, acc1 = {0, 0, 0, 0};
    float4 acc2 = {0, 0, 0, 0}, acc3 = {0, 0, 0, 0};
#pragma unroll 2
    for (int s = 0; s < CHUNK; s += 4) {
        float4 w = *(const float4*)(tt + s);
        float4 x0 = eo4[(size_t)(s + 0) * 256 + tid];
        float4 x1 = eo4[(size_t)(s + 1) * 256 + tid];
        float4 x2 = eo4[(size_t)(s + 2) * 256 + tid];
        float4 x3 = eo4[(size_t)(s + 3) * 256 + tid];
        acc0.x += w.x * x0.x; acc0.y += w.x * x0.y; acc0.z += w.x * x0.z; acc0.w += w.x * x0.w;
        acc1.x += w.y * x1.x; acc1.y += w.y * x1.y; acc1.z += w.y * x1.z; acc1.w += w.y * x1.w;
        acc2.x += w.z * x2.x; acc2.y += w.z * x2.y; acc2.z += w.z * x2.z; acc2.w += w.z * x2.w;
        acc3.x += w.w * x3.x; acc3.y += w.w * x3.y; acc3.z += w.w * x3.z; acc3.w += w.w * x3.w;
    }
    float4 acc;
    acc.x = (acc0.x + acc1.x) + (acc2.x + acc3.x);
    acc.y = (acc0.y + acc1.y) + (acc2.y + acc3.y);
    acc.z = (acc0.z + acc1.z) + (acc2.z + acc3.z);
    acc.w = (acc0.w + acc1.w) + (acc2.w + acc3.w);
    float4* dst = (float4*)(partials + ((size_t)blockIdx.x * BB + b) * HH);
    dst[tid] = acc;
}

// K4: finalize. scale_b = 1/(Sigma_t + 1e-20*Sigma_e)  (== reference's
// (1/Se)/(St/Se + 1e-20) order).
// Blocks 0..63:  attn1/attn2 = t*scale (one float4 of B*S per thread).
// Blocks 64..127: c_t reduction — block owns 64 float4s of B*H; 4 thread-
// groups each reduce 32 splits, LDS-combine, scale, store.
__global__ __launch_bounds__(256) void finalize_kernel(
    const float* __restrict__ tbuf, const float* __restrict__ partials,
    const float* __restrict__ stats, float* __restrict__ attn1,
    float* __restrict__ attn2, float* __restrict__ c_t)
{
    int tid = threadIdx.x;
    if (blockIdx.x < 64) {
        int g = blockIdx.x * 256 + tid;         // float4 index over B*S (16384)
        int b = g >> 10;                         // 1024 float4 per batch row
        float se = stats[b * 16 + 0];
        float st = stats[b * 16 + 1];
        float scale = 1.0f / (st + 1e-20f * se);
        float4 t = ((const float4*)tbuf)[g];
        float4 a;
        a.x = t.x * scale; a.y = t.y * scale; a.z = t.z * scale; a.w = t.w * scale;
        ((float4*)attn1)[g] = a;
        ((float4*)attn2)[g] = a;
    } else {
        int j2 = blockIdx.x - 64;                // 0..63
        int g = tid >> 6;                        // split-group 0..3
        int i = tid & 63;
        int ci = j2 * 64 + i;                    // float4 index over B*H (4096)
        const float4* p4 = (const float4*)partials;
        float4 acc = {0, 0, 0, 0};
        int s0 = g * (SPLIT / 4);
#pragma unroll 4
        for (int s = 0; s < SPLIT / 4; ++s) {
            float4 x = p4[(size_t)(s0 + s) * (BB * HH / 4) + ci];
            acc.x += x.x; acc.y += x.y; acc.z += x.z; acc.w += x.w;
        }
        __shared__ float4 sh[256];
        sh[tid] = acc;
        __syncthreads();
        if (g == 0) {
            float4 a0 = sh[i], a1 = sh[64 + i], a2 = sh[128 + i], a3 = sh[192 + i];
            int b = ci >> 8;                     // 256 float4 per batch
            float se = stats[b * 16 + 0];
            float st = stats[b * 16 + 1];
            float scale = 1.0f / (st + 1e-20f * se);
            float4 o;
            o.x = ((a0.x + a1.x) + (a2.x + a3.x)) * scale;
            o.y = ((a0.y + a1.y) + (a2.y + a3.y)) * scale;
            o.z = ((a0.z + a1.z) + (a2.z + a3.z)) * scale;
            o.w = ((a0.w + a1.w) + (a2.w + a3.w)) * scale;
            ((float4*)c_t)[ci] = o;
        }
    }
}

extern "C" void kernel_launch(void* const* d_in, const int* in_sizes, int n_in,
                              void* d_out, int out_size, void* d_ws, size_t ws_size,
                              hipStream_t stream)
{
    const float* s_t_hat  = (const float*)d_in[0];
    const float* enc_out  = (const float*)d_in[1];
    const float* enc_feat = (const float*)d_in[2];
    const float* mask     = (const float*)d_in[3];
    const float* cov      = (const float*)d_in[4];
    const float* W_dec    = (const float*)d_in[5];
    const float* b_dec    = (const float*)d_in[6];
    const float* W_c      = (const float*)d_in[7];
    const float* v        = (const float*)d_in[8];

    float* out    = (float*)d_out;
    float* c_t    = out;                    // B*H
    float* attn1  = out + BB * HH;          // B*S
    float* attn2  = attn1 + BB * SS;        // B*S
    float* scores = attn2 + BB * SS;        // B*S

    float* dec_fea  = (float*)d_ws;                 // B*H floats
    float* tbuf     = dec_fea + BB * HH;            // B*S floats (e*mask)
    float* stats    = tbuf + BB * SS;               // 16 b x {Sigma_e, Sigma_t}, 64B-padded
    float* partials = stats + 256;                  // SPLIT*B*H floats (8 MB)

    dec_fea_kernel<<<dim3(BB * HH / 4), 256, 0, stream>>>(s_t_hat, W_dec, b_dec, dec_fea, stats);
    scores_kernel<<<dim3(BB * SS / 16), 256, 0, stream>>>(enc_feat, dec_fea, cov, W_c, v, mask,
                                                          scores, tbuf, stats);
    context_partial_kernel<<<dim3(SPLIT, BB), 256, 0, stream>>>(enc_out, tbuf, partials);
    finalize_kernel<<<dim3(128), 256, 0, stream>>>(tbuf, partials, stats, attn1, attn2, c_t);
}